// Round 5
// baseline (427.839 us; speedup 1.0000x reference)
//
#include <hip/hip_runtime.h>
#include <hip/hip_bf16.h>

#define EMBED 1024
#define HEADS 16
#define HDIM 64
#define BATCH 4
#define SEQ 2048
#define ROWS (BATCH * SEQ) /* 8192 */
#define LOG2E 1.4426950408889634f

typedef __attribute__((ext_vector_type(8))) short bf16x8;  // 8 bf16 = 4 VGPRs
typedef __attribute__((ext_vector_type(4))) float f32x4;   // MFMA 16x16 acc

#define MFMA16(a, b, c) __builtin_amdgcn_mfma_f32_16x16x32_bf16(a, b, c, 0, 0, 0)

__device__ __forceinline__ unsigned short f2bf(float f) {
    union { float f; unsigned int u; } x; x.f = f;
    unsigned int r = x.u + 0x7fffu + ((x.u >> 16) & 1u); // RNE
    return (unsigned short)(r >> 16);
}

// packed (a,b) -> 2x bf16 in one dword; HW v_cvt_pk_bf16_f32 when available
__device__ __forceinline__ unsigned int pkbf(float a, float b) {
#if __has_builtin(__builtin_amdgcn_cvt_pk_bf16_f32)
    auto v = __builtin_amdgcn_cvt_pk_bf16_f32(a, b);
    unsigned int u; __builtin_memcpy(&u, &v, 4); return u;
#else
    union { __hip_bfloat162 h; unsigned int u; } c;
    c.h = __float22bfloat162_rn(make_float2(a, b)); return c.u;
#endif
}

// async global->LDS, 16 B per lane; lds dest = wave-uniform base + lane*16
__device__ __forceinline__ void gl2lds(const unsigned short* g, unsigned short* l) {
    __builtin_amdgcn_global_load_lds(
        (const __attribute__((address_space(1))) unsigned int*)g,
        (__attribute__((address_space(3))) unsigned int*)l, 16, 0, 0);
}

// ---------------------------------------------------------------------------
// Prep kernels
// ---------------------------------------------------------------------------
__global__ __launch_bounds__(256) void cvt_x_kernel(
    const float* __restrict__ in, unsigned short* __restrict__ out)
{
    int i = (blockIdx.x * 256 + threadIdx.x) * 4;
    float4 v = *(const float4*)(in + i);
    uint2 o; o.x = pkbf(v.x, v.y); o.y = pkbf(v.z, v.w);
    *(uint2*)(out + i) = o;
}

// W (K x N, row-major fp32) -> Wt (N x K, row-major bf16), 4 matrices.
__global__ __launch_bounds__(256) void wtrans_kernel(
    const float* __restrict__ W0, const float* __restrict__ W1,
    const float* __restrict__ W2, const float* __restrict__ W3,
    unsigned short* __restrict__ Wt)
{
    __shared__ float t[32][33];
    const float* W = (blockIdx.z == 0) ? W0 : (blockIdx.z == 1) ? W1
                   : (blockIdx.z == 2) ? W2 : W3;
    unsigned short* o = Wt + (size_t)blockIdx.z * EMBED * EMBED;
    int tx = threadIdx.x & 31, ty = threadIdx.x >> 5;
    int bx = blockIdx.x * 32, by = blockIdx.y * 32;
#pragma unroll
    for (int r = 0; r < 32; r += 8)
        t[ty + r][tx] = W[(size_t)(by + ty + r) * EMBED + bx + tx];
    __syncthreads();
#pragma unroll
    for (int r = 0; r < 32; r += 8)
        o[(size_t)(bx + ty + r) * EMBED + by + tx] = f2bf(t[tx][ty + r]);
}

// mask int32 -> u8 (0xFF / 0x00) for v_perm expansion to ushort AND-masks
__global__ __launch_bounds__(256) void cvt_mask_kernel(
    const int* __restrict__ in, unsigned char* __restrict__ out)
{
    int i = (blockIdx.x * 256 + threadIdx.x) * 4;
    int4 v = *(const int4*)(in + i);
    uchar4 o;
    o.x = v.x ? 0xFF : 0; o.y = v.y ? 0xFF : 0;
    o.z = v.z ? 0xFF : 0; o.w = v.w ? 0xFF : 0;
    *(uchar4*)(out + i) = o;
}

// ---------------------------------------------------------------------------
// bf16 MFMA GEMM, m97-style + XOR-swizzled LDS (swizzle via permuted gl2lds
// SOURCE address; DMA dest fixed base+16*lane). vmode=1: V projection writes
// output directly transposed to Vt[b][h][d][kseq] (packed 8B stores).
// ---------------------------------------------------------------------------
__device__ __forceinline__ void gemm_bf16_body(
    const unsigned short* __restrict__ A, const unsigned short* __restrict__ Bt,
    const float* __restrict__ bias,
    float* __restrict__ outF, unsigned short* __restrict__ outB, float scale,
    int vmode)
{
    __shared__ unsigned short As[128][32]; // 8 KB
    __shared__ unsigned short Bs[128][32];
    const int tid = threadIdx.x;
    const int lane = tid & 63, wid = tid >> 6;
    const int ln = lane & 15, lg = lane >> 4;
    const int wy = wid >> 1, wx = wid & 1;
    const int m0 = blockIdx.y * 128, n0 = blockIdx.x * 128;
    const int srow = tid >> 2;          // 0..63
    const int scol = (((tid & 3) ^ ((tid >> 2) & 3) ^ ((tid >> 4) & 3)) << 3);
    const unsigned short* Ap = A + (size_t)(m0 + srow) * EMBED + scol;
    const unsigned short* Bp = Bt + (size_t)(n0 + srow) * EMBED + scol;
    unsigned short* lA = &As[srow & ~15][0]; // wave-uniform
    unsigned short* lB = &Bs[srow & ~15][0];
    const int swg = ((lg ^ (ln & 3) ^ (ln >> 2)) << 3);

    f32x4 acc[4][4];
#pragma unroll
    for (int i = 0; i < 4; i++)
#pragma unroll
        for (int j = 0; j < 4; j++) acc[i][j] = (f32x4){0.f, 0.f, 0.f, 0.f};

    for (int k0 = 0; k0 < EMBED; k0 += 32) {
        __syncthreads();
        gl2lds(Ap + k0, lA);
        gl2lds(Ap + (size_t)64 * EMBED + k0, lA + 64 * 32);
        gl2lds(Bp + k0, lB);
        gl2lds(Bp + (size_t)64 * EMBED + k0, lB + 64 * 32);
        __syncthreads();
        bf16x8 af[4], bfr[4];
#pragma unroll
        for (int mi = 0; mi < 4; mi++)
            af[mi] = *(const bf16x8*)&As[wy * 64 + mi * 16 + ln][swg];
#pragma unroll
        for (int nj = 0; nj < 4; nj++)
            bfr[nj] = *(const bf16x8*)&Bs[wx * 64 + nj * 16 + ln][swg];
#pragma unroll
        for (int mi = 0; mi < 4; mi++)
#pragma unroll
            for (int nj = 0; nj < 4; nj++)
                acc[mi][nj] = MFMA16(af[mi], bfr[nj], acc[mi][nj]);
    }

#pragma unroll
    for (int mi = 0; mi < 4; mi++) {
#pragma unroll
        for (int nj = 0; nj < 4; nj++) {
            int row = m0 + wy * 64 + mi * 16 + lg * 4;
            int col = n0 + wx * 64 + nj * 16 + ln;
            float bv = bias[col];
            if (vmode) {
                // V output: Vt[(b*HEADS+h)*HDIM + d][s], 4 consecutive s/lane
                int bb = row >> 11, s = row & (SEQ - 1);
                int hh = col >> 6, dd = col & 63;
                unsigned short* dst = outB +
                    ((size_t)((bb * HEADS + hh) * HDIM + dd)) * SEQ + s;
                uint2 pw;
                pw.x = pkbf(acc[mi][nj][0] + bv, acc[mi][nj][1] + bv);
                pw.y = pkbf(acc[mi][nj][2] + bv, acc[mi][nj][3] + bv);
                *(uint2*)dst = pw;
            } else {
#pragma unroll
                for (int r = 0; r < 4; r++) {
                    float v = (acc[mi][nj][r] + bv) * scale;
                    if (outF) outF[(size_t)(row + r) * EMBED + col] = v;
                    else      outB[(size_t)(row + r) * EMBED + col] = f2bf(v);
                }
            }
        }
    }
}

__global__ __launch_bounds__(256) void qkv_gemm_kernel(
    const unsigned short* __restrict__ Xb, const unsigned short* __restrict__ Wt,
    const float* __restrict__ bq, const float* __restrict__ bk,
    const float* __restrict__ bv,
    unsigned short* __restrict__ Qb, unsigned short* __restrict__ Kb,
    unsigned short* __restrict__ Vt)
{
    int z = blockIdx.z;
    const unsigned short* Bt = Wt + (size_t)z * EMBED * EMBED;
    const float* bias = (z == 0) ? bq : (z == 1) ? bk : bv;
    unsigned short* out = (z == 0) ? Qb : (z == 1) ? Kb : Vt;
    // fold 1/sqrt(HDIM) AND log2(e) into Q so softmax uses raw v_exp_f32
    float scale = (z == 0) ? 0.125f * LOG2E : 1.0f;
    gemm_bf16_body(Xb, Bt, bias, nullptr, out, scale, z == 2);
}

__global__ __launch_bounds__(256) void out_gemm_kernel(
    const unsigned short* __restrict__ Ob, const unsigned short* __restrict__ Wto,
    const float* __restrict__ bo, float* __restrict__ out)
{
    gemm_bf16_body(Ob, Wto, bo, out, nullptr, 1.0f, 0);
}

// ---------------------------------------------------------------------------
// Flash attention, bf16 MFMA, no-max softmax, DOUBLE-BUFFERED K/V prefetch:
// DMA for tile t+1 issues before compute of tile t, so the vmcnt drain at the
// next barrier hits loads that aged a full compute phase. Mask applied as
// bitwise AND on packed bf16 P (v_perm expands 0xFF bytes -> 0xFFFF shorts).
// Row-sum l via MFMA against all-ones B (l lands in C-layout = O rows).
// ---------------------------------------------------------------------------
__global__ __launch_bounds__(256) void attn_mfma_kernel(
    const unsigned short* __restrict__ Qb, const unsigned short* __restrict__ Kb,
    const unsigned short* __restrict__ Vt, const unsigned char* __restrict__ mask8,
    unsigned short* __restrict__ Ob)
{
    __shared__ unsigned short Ks[2][64][64];  // [buf][kseq][d]  16 KB (swizzled)
    __shared__ unsigned short Vs[2][64][64];  // [buf][d][kseq]  16 KB (swizzled)
    __shared__ unsigned short Ps[4][32][64];  // per-wave [q][kseq], 16 KB
    const int tid = threadIdx.x;
    const int lane = tid & 63, wid = tid >> 6;
    const int ln = lane & 15, lg = lane >> 4;
    const int b = blockIdx.z, h = blockIdx.y;
    const int q0 = blockIdx.x * 128 + wid * 32;

    bf16x8 qf[2][2]; // A/B-frag: row q0+mi*16+ln, d = ks*32+lg*8..
#pragma unroll
    for (int mi = 0; mi < 2; mi++)
#pragma unroll
        for (int ks = 0; ks < 2; ks++)
            qf[mi][ks] = *(const bf16x8*)(Qb +
                (size_t)(b * SEQ + q0 + mi * 16 + ln) * EMBED + h * HDIM + ks * 32 + lg * 8);

    bf16x8 ones;
#pragma unroll
    for (int i = 0; i < 8; i++) ones[i] = (short)0x3F80; // bf16 1.0

    f32x4 o[2][4];
#pragma unroll
    for (int mi = 0; mi < 2; mi++)
#pragma unroll
        for (int dj = 0; dj < 4; dj++) o[mi][dj] = (f32x4){0.f, 0.f, 0.f, 0.f};
    f32x4 lacc[2] = {(f32x4){0.f, 0.f, 0.f, 0.f}, (f32x4){0.f, 0.f, 0.f, 0.f}};

    // staging: srow = tid>>3 (0..31), swizzled source chunk = (tid&7)^(srow&7)
    const int srow = tid >> 3;
    const int scolKV = (((tid & 7) ^ ((tid >> 3) & 7)) << 3);
    const unsigned short* Kp = Kb + (size_t)(b * SEQ + srow) * EMBED + h * HDIM + scolKV;
    const unsigned short* Vp = Vt + (size_t)((b * HEADS + h) * HDIM + srow) * SEQ + scolKV;
    unsigned short* lK[2] = {&Ks[0][srow & ~7][0], &Ks[1][srow & ~7][0]};
    unsigned short* lV[2] = {&Vs[0][srow & ~7][0], &Vs[1][srow & ~7][0]};

    const unsigned char* mq0 = mask8 + (size_t)b * SEQ * SEQ + (size_t)(q0 + ln) * SEQ;
    const unsigned char* mq1 = mq0 + (size_t)16 * SEQ;

    // swizzled fragment-read column for Ks/Vs
    const int swk = ((lg ^ (ln & 7)) << 3);

    // Ps swizzle offsets (2-way max)
    int pwr[4], prd[2];
#pragma unroll
    for (int nj = 0; nj < 4; nj++)
        pwr[nj] = (((2 * nj + (lg >> 1)) ^ (ln & 7)) << 3) + ((lg & 1) << 2);
#pragma unroll
    for (int ks = 0; ks < 2; ks++)
        prd[ks] = ((4 * ks + lg) ^ (ln & 7)) << 3;
    unsigned short* ps0 = &Ps[wid][ln][0];
    unsigned short* ps1 = &Ps[wid][16 + ln][0];

    // prologue: stage tile 0 into buf 0
    gl2lds(Kp, lK[0]);
    gl2lds(Kp + (size_t)32 * EMBED, lK[0] + 32 * 64);
    gl2lds(Vp, lV[0]);
    gl2lds(Vp + (size_t)32 * SEQ, lV[0] + 32 * 64);

    const int NT = SEQ / 64;
    for (int t = 0; t < NT; t++) {
        const int cur = t & 1;
        const int kt = t * 64;
        __syncthreads(); // drains buf[cur] DMA (aged); frees buf[cur^1]

        // mask loads first (vmcnt-FIFO: consumed before prefetch DMAs retire)
        unsigned int mw[2][4];
#pragma unroll
        for (int mi = 0; mi < 2; mi++) {
            const unsigned char* mq = (mi ? mq1 : mq0) + kt;
#pragma unroll
            for (int nj = 0; nj < 4; nj++)
                mw[mi][nj] = *(const unsigned int*)(mq + nj * 16 + lg * 4);
        }

        // prefetch tile t+1 into the other buffer
        if (t + 1 < NT) {
            const int nk = kt + 64;
            gl2lds(Kp + (size_t)nk * EMBED, lK[cur ^ 1]);
            gl2lds(Kp + (size_t)(nk + 32) * EMBED, lK[cur ^ 1] + 32 * 64);
            gl2lds(Vp + nk, lV[cur ^ 1]);
            gl2lds(Vp + (size_t)(32 * SEQ) + nk, lV[cur ^ 1] + 32 * 64);
        }

        // S^T: rows = kseq (nj*16+lg*4+reg), cols = q (mi*16+ln)
        f32x4 S[2][4];
#pragma unroll
        for (int nj = 0; nj < 4; nj++) {
            bf16x8 k0 = *(const bf16x8*)&Ks[cur][nj * 16 + ln][swk];
            bf16x8 k1 = *(const bf16x8*)&Ks[cur][nj * 16 + ln][swk ^ 32];
#pragma unroll
            for (int mi = 0; mi < 2; mi++) {
                f32x4 t2 = (f32x4){0.f, 0.f, 0.f, 0.f};
                t2 = MFMA16(k0, qf[mi][0], t2);
                t2 = MFMA16(k1, qf[mi][1], t2);
                S[mi][nj] = t2;
            }
        }

        // exp2 + packed cvt + mask-AND + packed P write
#pragma unroll
        for (int mi = 0; mi < 2; mi++) {
            unsigned short* psb = mi ? ps1 : ps0;
#pragma unroll
            for (int nj = 0; nj < 4; nj++) {
                float p0 = __builtin_amdgcn_exp2f(S[mi][nj][0]);
                float p1 = __builtin_amdgcn_exp2f(S[mi][nj][1]);
                float p2 = __builtin_amdgcn_exp2f(S[mi][nj][2]);
                float p3 = __builtin_amdgcn_exp2f(S[mi][nj][3]);
                unsigned int m = mw[mi][nj];
                unsigned int d0 = __builtin_amdgcn_perm(0u, m, 0x01010000u);
                unsigned int d1 = __builtin_amdgcn_perm(0u, m, 0x03030202u);
                uint2 pw;
                pw.x = pkbf(p0, p1) & d0;
                pw.y = pkbf(p2, p3) & d1;
                *(uint2*)(psb + pwr[nj]) = pw;
            }
        }

        // O += P @ V ; l += P @ ones
#pragma unroll
        for (int ks = 0; ks < 2; ks++) {
            bf16x8 p0 = *(const bf16x8*)(ps0 + prd[ks]);
            bf16x8 p1 = *(const bf16x8*)(ps1 + prd[ks]);
            lacc[0] = MFMA16(p0, ones, lacc[0]);
            lacc[1] = MFMA16(p1, ones, lacc[1]);
#pragma unroll
            for (int dj = 0; dj < 4; dj++) {
                bf16x8 vf = *(const bf16x8*)&Vs[cur][dj * 16 + ln][swk ^ (ks << 5)];
                o[0][dj] = MFMA16(p0, vf, o[0][dj]);
                o[1][dj] = MFMA16(p1, vf, o[1][dj]);
            }
        }
    }

#pragma unroll
    for (int mi = 0; mi < 2; mi++) {
        float l0 = 1.0f / lacc[mi][0];
        float l1 = 1.0f / lacc[mi][1];
        float l2 = 1.0f / lacc[mi][2];
        float l3 = 1.0f / lacc[mi][3];
#pragma unroll
        for (int dj = 0; dj < 4; dj++) {
            unsigned short* op = Ob + (size_t)(b * SEQ + q0 + mi * 16 + lg * 4) * EMBED
                                    + h * HDIM + dj * 16 + ln;
            op[0]         = f2bf(o[mi][dj][0] * l0);
            op[EMBED]     = f2bf(o[mi][dj][1] * l1);
            op[2 * EMBED] = f2bf(o[mi][dj][2] * l2);
            op[3 * EMBED] = f2bf(o[mi][dj][3] * l3);
        }
    }
}

extern "C" void kernel_launch(void* const* d_in, const int* in_sizes, int n_in,
                              void* d_out, int out_size, void* d_ws, size_t ws_size,
                              hipStream_t stream)
{
    const float* x  = (const float*)d_in[0];
    const int* mask = (const int*)d_in[1];
    const float* Wq = (const float*)d_in[2];
    const float* bq = (const float*)d_in[3];
    const float* Wk = (const float*)d_in[4];
    const float* bk = (const float*)d_in[5];
    const float* Wv = (const float*)d_in[6];
    const float* bv = (const float*)d_in[7];
    const float* Wo = (const float*)d_in[8];
    const float* bo = (const float*)d_in[9];
    float* outp = (float*)d_out;

    // Workspace layout (88 MB):
    //   [0,8)   Wt: 4x bf16 1024x1024 (transposed weights)
    //   [8,24)  mask8 (0xFF/0x00)
    //   [24,40) Xb (bf16 x) -- aliased by Ob after qkv consumes Xb
    //   [40,56) Qb  [56,72) Kb  [72,88) Vt (V written pre-transposed by qkv)
    char* ws = (char*)d_ws;
    unsigned short* Wt = (unsigned short*)(ws);
    unsigned char*  m8 = (unsigned char*)(ws + ((size_t)8 << 20));
    unsigned short* Xb = (unsigned short*)(ws + ((size_t)24 << 20));
    unsigned short* Ob = Xb;
    unsigned short* Qb = (unsigned short*)(ws + ((size_t)40 << 20));
    unsigned short* Kb = (unsigned short*)(ws + ((size_t)56 << 20));
    unsigned short* Vt = (unsigned short*)(ws + ((size_t)72 << 20));

    cvt_x_kernel<<<ROWS * EMBED / 1024, 256, 0, stream>>>(x, Xb);
    wtrans_kernel<<<dim3(32, 32, 4), 256, 0, stream>>>(Wq, Wk, Wv, Wo, Wt);
    cvt_mask_kernel<<<(size_t)BATCH * SEQ * SEQ / 1024, 256, 0, stream>>>(mask, m8);
    qkv_gemm_kernel<<<dim3(EMBED / 128, ROWS / 128, 3), 256, 0, stream>>>(
        Xb, Wt, bq, bk, bv, Qb, Kb, Vt);
    attn_mfma_kernel<<<dim3(SEQ / 128, HEADS, BATCH), 256, 0, stream>>>(
        Qb, Kb, Vt, m8, Ob);
    out_gemm_kernel<<<dim3(EMBED / 128, ROWS / 128), 256, 0, stream>>>(
        Ob, Wt + (size_t)3 * EMBED * EMBED, bo, outp);
}

// Round 6
// 397.897 us; speedup vs baseline: 1.0753x; 1.0753x over previous
//
#include <hip/hip_runtime.h>
#include <hip/hip_bf16.h>

#define EMBED 1024
#define HEADS 16
#define HDIM 64
#define BATCH 4
#define SEQ 2048
#define ROWS (BATCH * SEQ) /* 8192 */
#define LOG2E 1.4426950408889634f

typedef __attribute__((ext_vector_type(8))) short bf16x8;  // 8 bf16 = 4 VGPRs
typedef __attribute__((ext_vector_type(4))) float f32x4;   // MFMA 16x16 acc

#define MFMA16(a, b, c) __builtin_amdgcn_mfma_f32_16x16x32_bf16(a, b, c, 0, 0, 0)

__device__ __forceinline__ unsigned short f2bf(float f) {
    union { float f; unsigned int u; } x; x.f = f;
    unsigned int r = x.u + 0x7fffu + ((x.u >> 16) & 1u); // RNE
    return (unsigned short)(r >> 16);
}

// packed (a,b) -> 2x bf16 in one dword; HW v_cvt_pk_bf16_f32 when available
__device__ __forceinline__ unsigned int pkbf(float a, float b) {
#if __has_builtin(__builtin_amdgcn_cvt_pk_bf16_f32)
    auto v = __builtin_amdgcn_cvt_pk_bf16_f32(a, b);
    unsigned int u; __builtin_memcpy(&u, &v, 4); return u;
#else
    union { __hip_bfloat162 h; unsigned int u; } c;
    c.h = __float22bfloat162_rn(make_float2(a, b)); return c.u;
#endif
}

// async global->LDS, 16 B per lane; lds dest = wave-uniform base + lane*16
__device__ __forceinline__ void gl2lds(const unsigned short* g, unsigned short* l) {
    __builtin_amdgcn_global_load_lds(
        (const __attribute__((address_space(1))) unsigned int*)g,
        (__attribute__((address_space(3))) unsigned int*)l, 16, 0, 0);
}

// ---------------------------------------------------------------------------
// Fused prep: [0,8192) cvt_x | [8192,24576) cvt_mask | [24576,28672) wtrans
// ---------------------------------------------------------------------------
#define XBLK 8192
#define MBLK 16384
#define WBLK 4096

__global__ __launch_bounds__(256) void prep_kernel(
    const float* __restrict__ x, const int* __restrict__ mask,
    const float* __restrict__ W0, const float* __restrict__ W1,
    const float* __restrict__ W2, const float* __restrict__ W3,
    unsigned short* __restrict__ Xb, unsigned char* __restrict__ m8,
    unsigned short* __restrict__ Wt)
{
    __shared__ float t[32][33];
    const int bid = blockIdx.x;
    if (bid < XBLK) {
        int i = (bid * 256 + threadIdx.x) * 4;
        float4 v = *(const float4*)(x + i);
        uint2 o; o.x = pkbf(v.x, v.y); o.y = pkbf(v.z, v.w);
        *(uint2*)(Xb + i) = o;
    } else if (bid < XBLK + MBLK) {
        int i = ((bid - XBLK) * 256 + threadIdx.x) * 4;
        int4 v = *(const int4*)(mask + i);
        uchar4 o;
        o.x = v.x ? 0xFF : 0; o.y = v.y ? 0xFF : 0;
        o.z = v.z ? 0xFF : 0; o.w = v.w ? 0xFF : 0;
        *(uchar4*)(m8 + i) = o;
    } else {
        int f = bid - XBLK - MBLK;           // 0..4095
        int z = f >> 10, rem = f & 1023;
        const float* W = (z == 0) ? W0 : (z == 1) ? W1 : (z == 2) ? W2 : W3;
        unsigned short* o = Wt + (size_t)z * EMBED * EMBED;
        int tx = threadIdx.x & 31, ty = threadIdx.x >> 5;
        int bx = (rem & 31) * 32, by = (rem >> 5) * 32;  // bx: n, by: k
#pragma unroll
        for (int r = 0; r < 32; r += 8)
            t[ty + r][tx] = W[(size_t)(by + ty + r) * EMBED + bx + tx];
        __syncthreads();
#pragma unroll
        for (int r = 0; r < 32; r += 8)
            o[(size_t)(bx + ty + r) * EMBED + by + tx] = f2bf(t[tx][ty + r]);
    }
}

// ---------------------------------------------------------------------------
// bf16 MFMA GEMM: 128x128 tile, BK=64 (half the barriers of BK=32), unpadded
// XOR-swizzled LDS (128-B rows, phys_chunk = logical ^ (row&7)); staged via
// gl2lds with per-lane swizzled SOURCE addresses. 4 waves, 4x4 16x16x32.
// vmode=1: V projection writes output transposed to Vt[b][h][d][kseq].
// ---------------------------------------------------------------------------
__device__ __forceinline__ void gemm_bf16_body(
    const unsigned short* __restrict__ A, const unsigned short* __restrict__ Bt,
    const float* __restrict__ bias,
    float* __restrict__ outF, unsigned short* __restrict__ outB, float scale,
    int vmode)
{
    __shared__ unsigned short As[128][64]; // 16 KB
    __shared__ unsigned short Bs[128][64]; // 16 KB
    const int tid = threadIdx.x;
    const int lane = tid & 63, wid = tid >> 6;
    const int ln = lane & 15, lg = lane >> 4;
    const int wy = wid >> 1, wx = wid & 1;
    const int m0 = blockIdx.y * 128, n0 = blockIdx.x * 128;
    // staging: lane stages row r0(+8*is), phys chunk = lane&7,
    // swizzled source logical chunk = (lane&7) ^ (r&7), r&7 = lane>>3
    const int r0 = wid * 32 + (lane >> 3);
    const int scol = (((lane & 7) ^ ((lane >> 3) & 7)) << 3);
    const unsigned short* Ap = A + (size_t)(m0 + r0) * EMBED + scol;
    const unsigned short* Bp = Bt + (size_t)(n0 + r0) * EMBED + scol;
    unsigned short* lA = &As[wid * 32][0]; // wave-uniform
    unsigned short* lB = &Bs[wid * 32][0];

    f32x4 acc[4][4];
#pragma unroll
    for (int i = 0; i < 4; i++)
#pragma unroll
        for (int j = 0; j < 4; j++) acc[i][j] = (f32x4){0.f, 0.f, 0.f, 0.f};

    for (int k0 = 0; k0 < EMBED; k0 += 64) {
        __syncthreads();
#pragma unroll
        for (int is = 0; is < 4; is++) {
            gl2lds(Ap + k0 + (size_t)(is * 8) * EMBED, lA + is * 8 * 64);
            gl2lds(Bp + k0 + (size_t)(is * 8) * EMBED, lB + is * 8 * 64);
        }
        __syncthreads();
        bf16x8 af[2][4], bfr[2][4];
#pragma unroll
        for (int s = 0; s < 2; s++) {
#pragma unroll
            for (int mi = 0; mi < 4; mi++)
                af[s][mi] = *(const bf16x8*)
                    &As[wy * 64 + mi * 16 + ln][(((lg + 4 * s) ^ (ln & 7)) << 3)];
#pragma unroll
            for (int nj = 0; nj < 4; nj++)
                bfr[s][nj] = *(const bf16x8*)
                    &Bs[wx * 64 + nj * 16 + ln][(((lg + 4 * s) ^ (ln & 7)) << 3)];
        }
#pragma unroll
        for (int s = 0; s < 2; s++)
#pragma unroll
            for (int mi = 0; mi < 4; mi++)
#pragma unroll
                for (int nj = 0; nj < 4; nj++)
                    acc[mi][nj] = MFMA16(af[s][mi], bfr[s][nj], acc[mi][nj]);
    }

#pragma unroll
    for (int mi = 0; mi < 4; mi++) {
#pragma unroll
        for (int nj = 0; nj < 4; nj++) {
            int row = m0 + wy * 64 + mi * 16 + lg * 4;
            int col = n0 + wx * 64 + nj * 16 + ln;
            float bv = bias[col];
            if (vmode) {
                // V output: Vt[(b*HEADS+h)*HDIM + d][s], 4 consecutive s/lane
                int bb = row >> 11, s = row & (SEQ - 1);
                int hh = col >> 6, dd = col & 63;
                unsigned short* dst = outB +
                    ((size_t)((bb * HEADS + hh) * HDIM + dd)) * SEQ + s;
                uint2 pw;
                pw.x = pkbf(acc[mi][nj][0] + bv, acc[mi][nj][1] + bv);
                pw.y = pkbf(acc[mi][nj][2] + bv, acc[mi][nj][3] + bv);
                *(uint2*)dst = pw;
            } else {
#pragma unroll
                for (int r = 0; r < 4; r++) {
                    float v = (acc[mi][nj][r] + bv) * scale;
                    if (outF) outF[(size_t)(row + r) * EMBED + col] = v;
                    else      outB[(size_t)(row + r) * EMBED + col] = f2bf(v);
                }
            }
        }
    }
}

__global__ __launch_bounds__(256) void qkv_gemm_kernel(
    const unsigned short* __restrict__ Xb, const unsigned short* __restrict__ Wt,
    const float* __restrict__ bq, const float* __restrict__ bk,
    const float* __restrict__ bv,
    unsigned short* __restrict__ Qb, unsigned short* __restrict__ Kb,
    unsigned short* __restrict__ Vt)
{
    int z = blockIdx.z;
    const unsigned short* Bt = Wt + (size_t)z * EMBED * EMBED;
    const float* bias = (z == 0) ? bq : (z == 1) ? bk : bv;
    unsigned short* out = (z == 0) ? Qb : (z == 1) ? Kb : Vt;
    // fold 1/sqrt(HDIM) AND log2(e) into Q so softmax uses raw v_exp_f32
    float scale = (z == 0) ? 0.125f * LOG2E : 1.0f;
    gemm_bf16_body(Xb, Bt, bias, nullptr, out, scale, z == 2);
}

__global__ __launch_bounds__(256) void out_gemm_kernel(
    const unsigned short* __restrict__ Ob, const unsigned short* __restrict__ Wto,
    const float* __restrict__ bo, float* __restrict__ out)
{
    gemm_bf16_body(Ob, Wto, bo, out, nullptr, 1.0f, 0);
}

// ---------------------------------------------------------------------------
// Flash attention, bf16 MFMA, no-max softmax. SINGLE-buffered K/V (32 KB LDS
// -> 5 blocks/CU; R5 proved implicit cross-wave overlap beats explicit dbuf
// at lower occupancy). Mask applied as bitwise AND on packed bf16 P (v_perm
// expands 0xFF bytes -> 0xFFFF shorts). Row-sum l via MFMA against all-ones
// B (l lands in C-layout = O rows; no epilogue shuffles).
// ---------------------------------------------------------------------------
__global__ __launch_bounds__(256) void attn_mfma_kernel(
    const unsigned short* __restrict__ Qb, const unsigned short* __restrict__ Kb,
    const unsigned short* __restrict__ Vt, const unsigned char* __restrict__ mask8,
    unsigned short* __restrict__ Ob)
{
    __shared__ unsigned short Ks[64][64];    // [kseq][d]  8 KB (swizzled)
    __shared__ unsigned short Vs[64][64];    // [d][kseq]  8 KB (swizzled)
    __shared__ unsigned short Ps[4][32][64]; // per-wave [q][kseq], 16 KB
    const int tid = threadIdx.x;
    const int lane = tid & 63, wid = tid >> 6;
    const int ln = lane & 15, lg = lane >> 4;
    const int b = blockIdx.z, h = blockIdx.y;
    const int q0 = blockIdx.x * 128 + wid * 32;

    bf16x8 qf[2][2]; // A/B-frag: row q0+mi*16+ln, d = ks*32+lg*8..
#pragma unroll
    for (int mi = 0; mi < 2; mi++)
#pragma unroll
        for (int ks = 0; ks < 2; ks++)
            qf[mi][ks] = *(const bf16x8*)(Qb +
                (size_t)(b * SEQ + q0 + mi * 16 + ln) * EMBED + h * HDIM + ks * 32 + lg * 8);

    bf16x8 ones;
#pragma unroll
    for (int i = 0; i < 8; i++) ones[i] = (short)0x3F80; // bf16 1.0

    f32x4 o[2][4];
#pragma unroll
    for (int mi = 0; mi < 2; mi++)
#pragma unroll
        for (int dj = 0; dj < 4; dj++) o[mi][dj] = (f32x4){0.f, 0.f, 0.f, 0.f};
    f32x4 lacc[2] = {(f32x4){0.f, 0.f, 0.f, 0.f}, (f32x4){0.f, 0.f, 0.f, 0.f}};

    // staging: srow = tid>>3 (0..31), swizzled source chunk = (tid&7)^(srow&7)
    const int srow = tid >> 3;
    const int scolKV = (((tid & 7) ^ ((tid >> 3) & 7)) << 3);
    const unsigned short* Kp = Kb + (size_t)(b * SEQ + srow) * EMBED + h * HDIM + scolKV;
    const unsigned short* Vp = Vt + (size_t)((b * HEADS + h) * HDIM + srow) * SEQ + scolKV;
    unsigned short* lK = &Ks[srow & ~7][0]; // wave-uniform
    unsigned short* lV = &Vs[srow & ~7][0];

    const unsigned char* mq0 = mask8 + (size_t)b * SEQ * SEQ + (size_t)(q0 + ln) * SEQ;
    const unsigned char* mq1 = mq0 + (size_t)16 * SEQ;

    // swizzled fragment-read column for Ks/Vs
    const int swk = ((lg ^ (ln & 7)) << 3);

    // Ps swizzle offsets (2-way max)
    int pwr[4], prd[2];
#pragma unroll
    for (int nj = 0; nj < 4; nj++)
        pwr[nj] = (((2 * nj + (lg >> 1)) ^ (ln & 7)) << 3) + ((lg & 1) << 2);
#pragma unroll
    for (int ks = 0; ks < 2; ks++)
        prd[ks] = ((4 * ks + lg) ^ (ln & 7)) << 3;
    unsigned short* ps0 = &Ps[wid][ln][0];
    unsigned short* ps1 = &Ps[wid][16 + ln][0];

    for (int kt = 0; kt < SEQ; kt += 64) {
        // mask loads: independent of LDS, overlap barrier waits
        unsigned int mw[2][4];
#pragma unroll
        for (int mi = 0; mi < 2; mi++) {
            const unsigned char* mq = (mi ? mq1 : mq0) + kt;
#pragma unroll
            for (int nj = 0; nj < 4; nj++)
                mw[mi][nj] = *(const unsigned int*)(mq + nj * 16 + lg * 4);
        }

        __syncthreads(); // previous tile fully consumed
        gl2lds(Kp + (size_t)kt * EMBED, lK);
        gl2lds(Kp + (size_t)(kt + 32) * EMBED, lK + 32 * 64);
        gl2lds(Vp + kt, lV);
        gl2lds(Vp + (size_t)32 * SEQ + kt, lV + 32 * 64);
        __syncthreads(); // DMA drained

        // S^T: rows = kseq (nj*16+lg*4+reg), cols = q (mi*16+ln)
        f32x4 S[2][4];
#pragma unroll
        for (int nj = 0; nj < 4; nj++) {
            bf16x8 k0 = *(const bf16x8*)&Ks[nj * 16 + ln][swk];
            bf16x8 k1 = *(const bf16x8*)&Ks[nj * 16 + ln][swk ^ 32];
#pragma unroll
            for (int mi = 0; mi < 2; mi++) {
                f32x4 t2 = (f32x4){0.f, 0.f, 0.f, 0.f};
                t2 = MFMA16(k0, qf[mi][0], t2);
                t2 = MFMA16(k1, qf[mi][1], t2);
                S[mi][nj] = t2;
            }
        }

        // exp2 + packed cvt + mask-AND + packed P write
#pragma unroll
        for (int mi = 0; mi < 2; mi++) {
            unsigned short* psb = mi ? ps1 : ps0;
#pragma unroll
            for (int nj = 0; nj < 4; nj++) {
                float p0 = __builtin_amdgcn_exp2f(S[mi][nj][0]);
                float p1 = __builtin_amdgcn_exp2f(S[mi][nj][1]);
                float p2 = __builtin_amdgcn_exp2f(S[mi][nj][2]);
                float p3 = __builtin_amdgcn_exp2f(S[mi][nj][3]);
                unsigned int m = mw[mi][nj];
                unsigned int d0 = __builtin_amdgcn_perm(0u, m, 0x01010000u);
                unsigned int d1 = __builtin_amdgcn_perm(0u, m, 0x03030202u);
                uint2 pw;
                pw.x = pkbf(p0, p1) & d0;
                pw.y = pkbf(p2, p3) & d1;
                *(uint2*)(psb + pwr[nj]) = pw;
            }
        }

        // O += P @ V ; l += P @ ones
#pragma unroll
        for (int ks = 0; ks < 2; ks++) {
            bf16x8 p0 = *(const bf16x8*)(ps0 + prd[ks]);
            bf16x8 p1 = *(const bf16x8*)(ps1 + prd[ks]);
            lacc[0] = MFMA16(p0, ones, lacc[0]);
            lacc[1] = MFMA16(p1, ones, lacc[1]);
#pragma unroll
            for (int dj = 0; dj < 4; dj++) {
                bf16x8 vf = *(const bf16x8*)&Vs[dj * 16 + ln][swk ^ (ks << 5)];
                o[0][dj] = MFMA16(p0, vf, o[0][dj]);
                o[1][dj] = MFMA16(p1, vf, o[1][dj]);
            }
        }
    }

#pragma unroll
    for (int mi = 0; mi < 2; mi++) {
        float l0 = 1.0f / lacc[mi][0];
        float l1 = 1.0f / lacc[mi][1];
        float l2 = 1.0f / lacc[mi][2];
        float l3 = 1.0f / lacc[mi][3];
#pragma unroll
        for (int dj = 0; dj < 4; dj++) {
            unsigned short* op = Ob + (size_t)(b * SEQ + q0 + mi * 16 + lg * 4) * EMBED
                                    + h * HDIM + dj * 16 + ln;
            op[0]         = f2bf(o[mi][dj][0] * l0);
            op[EMBED]     = f2bf(o[mi][dj][1] * l1);
            op[2 * EMBED] = f2bf(o[mi][dj][2] * l2);
            op[3 * EMBED] = f2bf(o[mi][dj][3] * l3);
        }
    }
}

extern "C" void kernel_launch(void* const* d_in, const int* in_sizes, int n_in,
                              void* d_out, int out_size, void* d_ws, size_t ws_size,
                              hipStream_t stream)
{
    const float* x  = (const float*)d_in[0];
    const int* mask = (const int*)d_in[1];
    const float* Wq = (const float*)d_in[2];
    const float* bq = (const float*)d_in[3];
    const float* Wk = (const float*)d_in[4];
    const float* bk = (const float*)d_in[5];
    const float* Wv = (const float*)d_in[6];
    const float* bv = (const float*)d_in[7];
    const float* Wo = (const float*)d_in[8];
    const float* bo = (const float*)d_in[9];
    float* outp = (float*)d_out;

    // Workspace layout (88 MB):
    //   [0,8)   Wt: 4x bf16 1024x1024 (transposed weights)
    //   [8,24)  mask8 (0xFF/0x00)
    //   [24,40) Xb (bf16 x) -- aliased by Ob after qkv consumes Xb
    //   [40,56) Qb  [56,72) Kb  [72,88) Vt (V written pre-transposed by qkv)
    char* ws = (char*)d_ws;
    unsigned short* Wt = (unsigned short*)(ws);
    unsigned char*  m8 = (unsigned char*)(ws + ((size_t)8 << 20));
    unsigned short* Xb = (unsigned short*)(ws + ((size_t)24 << 20));
    unsigned short* Ob = Xb;
    unsigned short* Qb = (unsigned short*)(ws + ((size_t)40 << 20));
    unsigned short* Kb = (unsigned short*)(ws + ((size_t)56 << 20));
    unsigned short* Vt = (unsigned short*)(ws + ((size_t)72 << 20));

    prep_kernel<<<XBLK + MBLK + WBLK, 256, 0, stream>>>(
        x, mask, Wq, Wk, Wv, Wo, Xb, m8, Wt);
    qkv_gemm_kernel<<<dim3(EMBED / 128, ROWS / 128, 3), 256, 0, stream>>>(
        Xb, Wt, bq, bk, bv, Qb, Kb, Vt);
    attn_mfma_kernel<<<dim3(SEQ / 128, HEADS, BATCH), 256, 0, stream>>>(
        Qb, Kb, Vt, m8, Ob);
    out_gemm_kernel<<<dim3(EMBED / 128, ROWS / 128), 256, 0, stream>>>(
        Ob, Wt + (size_t)3 * EMBED * EMBED, bo, outp);
}